// Round 1
// baseline (131.932 us; speedup 1.0000x reference)
//
#include <hip/hip_runtime.h>

#define B_  16
#define LQ  256
#define LK  256
#define QD  256
#define HD  128
#define VD  128

// 2*log2(e): stored projections are pre-scaled so exp2(qp'+kp') = e^{2(qp+kp)}
#define SCALE2 2.8853900817779268f
#define L2E    1.4426950408889634f

__device__ __forceinline__ float fast_exp2(float x) { return __builtin_amdgcn_exp2f(x); }
__device__ __forceinline__ float fast_rcp(float x)  { return __builtin_amdgcn_rcpf(x); }

// ---------------------------------------------------------------------------
// Kernel A: projections.
//   TOUT=true : Y[b*HD+h][q] = SCALE2 * sum_k X[b*LQ+q][k] * W[k][h]   (transposed out)
//   TOUT=false: Y[m][h]      = SCALE2 * sum_k X[m][k]      * W[k][h]   (normal out)
// Tile: 32 rows (m) x 128 cols (h), K chunked by 32. 4x4 register tile/thread.
// ---------------------------------------------------------------------------
template <bool TOUT>
__device__ __forceinline__ void proj_body(const float* __restrict__ X,
                                          const float* __restrict__ W,
                                          float* __restrict__ Y,
                                          float (&Xs)[32][36],   // [kk][row] transposed, stride 36 keeps 16B align
                                          float (&Ws)[32][128])  // [kk][h]
{
    const int t  = threadIdx.x;
    const int m0 = blockIdx.x * 32;

    float acc[4][4];
#pragma unroll
    for (int i = 0; i < 4; i++)
#pragma unroll
        for (int j = 0; j < 4; j++) acc[i][j] = 0.f;

    const int xr = t >> 3;          // 0..31 row for X staging
    const int xj = (t & 7) << 2;    // 0..28 k-offset for X staging
    const int wk = t >> 5;          // 0..7 base kk for W staging
    const int wh = (t & 31) << 2;   // 0..124 h for W staging

    // compute-phase fragment offsets
    const int a4 = TOUT ? ((t >> 3) << 2) : ((t >> 5) << 2);  // TOUT: h (0..124), else m (0..28)
    const int b4 = TOUT ? ((t & 7) << 2)  : ((t & 31) << 2);  // TOUT: m (0..28),  else h (0..124)

    for (int c = 0; c < 8; c++) {
        const int k0 = c << 5;
        const float4 xv  = *(const float4*)(X + (size_t)(m0 + xr) * QD + k0 + xj);
        const float4 wv0 = *(const float4*)(W + (size_t)(k0 + wk) * HD + wh);
        const float4 wv1 = *(const float4*)(W + (size_t)(k0 + wk + 8) * HD + wh);
        const float4 wv2 = *(const float4*)(W + (size_t)(k0 + wk + 16) * HD + wh);
        const float4 wv3 = *(const float4*)(W + (size_t)(k0 + wk + 24) * HD + wh);
        __syncthreads();  // previous iteration's reads done before overwrite
        Xs[xj + 0][xr] = xv.x;
        Xs[xj + 1][xr] = xv.y;
        Xs[xj + 2][xr] = xv.z;
        Xs[xj + 3][xr] = xv.w;
        *(float4*)&Ws[wk][wh]      = wv0;
        *(float4*)&Ws[wk + 8][wh]  = wv1;
        *(float4*)&Ws[wk + 16][wh] = wv2;
        *(float4*)&Ws[wk + 24][wh] = wv3;
        __syncthreads();

#pragma unroll
        for (int kk = 0; kk < 32; kk++) {
            float4 av, bv;
            if (TOUT) {
                av = *(const float4*)&Ws[kk][a4];  // h fragment
                bv = *(const float4*)&Xs[kk][b4];  // q fragment
            } else {
                av = *(const float4*)&Xs[kk][a4];  // m fragment
                bv = *(const float4*)&Ws[kk][b4];  // h fragment
            }
            const float a[4] = {av.x, av.y, av.z, av.w};
            const float b[4] = {bv.x, bv.y, bv.z, bv.w};
#pragma unroll
            for (int i = 0; i < 4; i++)
#pragma unroll
                for (int j = 0; j < 4; j++) acc[i][j] += a[i] * b[j];
        }
    }

    if (TOUT) {
        const int b  = m0 >> 8;        // batch
        const int q0 = m0 & 255;       // q tile base
#pragma unroll
        for (int i = 0; i < 4; i++) {
            float4 o = make_float4(acc[i][0] * SCALE2, acc[i][1] * SCALE2,
                                   acc[i][2] * SCALE2, acc[i][3] * SCALE2);
            *(float4*)(Y + (size_t)(b * HD + a4 + i) * LQ + q0 + b4) = o;
        }
    } else {
#pragma unroll
        for (int i = 0; i < 4; i++) {
            float4 o = make_float4(acc[i][0] * SCALE2, acc[i][1] * SCALE2,
                                   acc[i][2] * SCALE2, acc[i][3] * SCALE2);
            *(float4*)(Y + (size_t)(m0 + a4 + i) * HD + b4) = o;
        }
    }
}

__global__ __launch_bounds__(256) void proj_kernel(const float* __restrict__ query,
                                                   const float* __restrict__ key,
                                                   const float* __restrict__ Wq,
                                                   const float* __restrict__ Wk,
                                                   float* __restrict__ qp_t,
                                                   float* __restrict__ kp)
{
    __shared__ float Xs[32][36];
    __shared__ float Ws[32][128];
    if (blockIdx.y == 0)
        proj_body<true>(query, Wq, qp_t, Xs, Ws);
    else
        proj_body<false>(key, Wk, kp, Xs, Ws);
}

// ---------------------------------------------------------------------------
// Kernel B: score (tanh dot v) + softmax over q + context bmm.
// Block = (b, 8 consecutive k). 256 threads, thread = q.
// ---------------------------------------------------------------------------
#define CTX_SIZE (B_ * LK * VD)

__global__ __launch_bounds__(256) void attn_kernel(const float* __restrict__ qp_t,
                                                   const float* __restrict__ kp,
                                                   const float* __restrict__ v,
                                                   const float* __restrict__ value,
                                                   float* __restrict__ out)
{
    __shared__ float score_s[8][257];
    __shared__ float attn_T[256][9];

    const int t  = threadIdx.x;
    const int b  = blockIdx.x >> 5;
    const int k0 = (blockIdx.x & 31) << 3;

    const float* qpb = qp_t + (size_t)b * HD * LQ;          // [h][q]
    const float* kpb = kp + ((size_t)b * LK + k0) * HD;     // rows k0..k0+7

    // ---- Phase 1: score[k][q] = sumv - 2 * sum_h v[h] / (1 + e^{2(qp+kp)}) ----
    float acc[8];
#pragma unroll
    for (int k = 0; k < 8; k++) acc[k] = 0.f;

    const int q = t;
    for (int h0 = 0; h0 < HD; h0 += 8) {
        float qv[8];
#pragma unroll
        for (int j = 0; j < 8; j++) qv[j] = qpb[(size_t)(h0 + j) * LQ + q];
#pragma unroll
        for (int k = 0; k < 8; k++) {
#pragma unroll
            for (int j = 0; j < 8; j++) {
                const float e = fast_exp2(qv[j] + kpb[k * HD + h0 + j]);  // e^{2x}
                acc[k] += v[h0 + j] * fast_rcp(e + 1.0f);
            }
        }
    }

    float sumv = 0.f;  // wave-uniform
#pragma unroll
    for (int h = 0; h < HD; h++) sumv += v[h];

#pragma unroll
    for (int k = 0; k < 8; k++) score_s[k][q] = sumv - 2.f * acc[k];
    __syncthreads();

    // ---- Phase 2: softmax over q per k; write attention out + attn_T in LDS ----
    const int w = t >> 6, lane = t & 63;
#pragma unroll
    for (int kk = 0; kk < 2; kk++) {
        const int k = w * 2 + kk;
        float x0 = score_s[k][lane];
        float x1 = score_s[k][lane + 64];
        float x2 = score_s[k][lane + 128];
        float x3 = score_s[k][lane + 192];
        float m = fmaxf(fmaxf(x0, x1), fmaxf(x2, x3));
#pragma unroll
        for (int off = 32; off >= 1; off >>= 1) m = fmaxf(m, __shfl_xor(m, off));
        float e0 = fast_exp2((x0 - m) * L2E);
        float e1 = fast_exp2((x1 - m) * L2E);
        float e2 = fast_exp2((x2 - m) * L2E);
        float e3 = fast_exp2((x3 - m) * L2E);
        float s = e0 + e1 + e2 + e3;
#pragma unroll
        for (int off = 32; off >= 1; off >>= 1) s += __shfl_xor(s, off);
        const float rs = fast_rcp(s);
        e0 *= rs; e1 *= rs; e2 *= rs; e3 *= rs;
        attn_T[lane][k]       = e0;
        attn_T[lane + 64][k]  = e1;
        attn_T[lane + 128][k] = e2;
        attn_T[lane + 192][k] = e3;
        float* ao = out + CTX_SIZE + ((size_t)(b * LK + k0 + k)) * LQ;
        ao[lane]       = e0;
        ao[lane + 64]  = e1;
        ao[lane + 128] = e2;
        ao[lane + 192] = e3;
    }
    __syncthreads();

    // ---- Phase 3: context[k][vd] = sum_q attn[k][q] * value[q][vd] ----
    const int kg  = t >> 5;          // 0..7 local k
    const int vd4 = (t & 31) << 2;   // 0..124
    const float* valb = value + (size_t)b * LQ * VD;
    float4 cacc = make_float4(0.f, 0.f, 0.f, 0.f);
#pragma unroll 4
    for (int q2 = 0; q2 < LQ; q2++) {
        const float a = attn_T[q2][kg];
        const float4 vv = *(const float4*)(valb + (size_t)q2 * VD + vd4);
        cacc.x += a * vv.x;
        cacc.y += a * vv.y;
        cacc.z += a * vv.z;
        cacc.w += a * vv.w;
    }
    *(float4*)(out + ((size_t)(b * LK + k0 + kg)) * VD + vd4) = cacc;
}

extern "C" void kernel_launch(void* const* d_in, const int* in_sizes, int n_in,
                              void* d_out, int out_size, void* d_ws, size_t ws_size,
                              hipStream_t stream)
{
    const float* query = (const float*)d_in[0];
    const float* key   = (const float*)d_in[1];
    const float* value = (const float*)d_in[2];
    const float* Wq    = (const float*)d_in[3];
    const float* Wk    = (const float*)d_in[4];
    const float* v     = (const float*)d_in[5];
    float* out = (float*)d_out;

    float* qp_t = (float*)d_ws;                      // [B][HD][LQ] = 524288 floats
    float* kpw  = qp_t + (size_t)B_ * HD * LQ;       // [B][LK][HD] = 524288 floats

    proj_kernel<<<dim3(128, 2), 256, 0, stream>>>(query, key, Wq, Wk, qp_t, kpw);
    attn_kernel<<<dim3(512), 256, 0, stream>>>(qp_t, kpw, v, value, out);
}

// Round 2
// 106.099 us; speedup vs baseline: 1.2435x; 1.2435x over previous
//
#include <hip/hip_runtime.h>

#define B_  16
#define LQ  256
#define LK  256
#define QD  256
#define HD  128
#define VD  128

// 2*log2(e): exp2(SCALE2*x) = e^{2x}
#define SCALE2 2.8853900817779268f
#define L2E    1.4426950408889634f
#define CTX_SIZE (B_ * LK * VD)

__device__ __forceinline__ float fast_exp2(float x) { return __builtin_amdgcn_exp2f(x); }
__device__ __forceinline__ float fast_rcp(float x)  { return __builtin_amdgcn_rcpf(x); }

// ---------------------------------------------------------------------------
// proj_kernel: 1024 blocks x 256 threads.
//   blocks [0,512):   qe_t[b][h][q] = exp2(SCALE2 * (query @ Wq))   (transposed)
//   blocks [512,1024): ke[b][k][h]  = exp2(SCALE2 * (key @ Wk))
// Block tile: 8 rows x 128 h, split-K: wave w sums k in [w*64, w*64+64).
// ---------------------------------------------------------------------------
__global__ __launch_bounds__(256) void proj_kernel(const float* __restrict__ query,
                                                   const float* __restrict__ key,
                                                   const float* __restrict__ Wq,
                                                   const float* __restrict__ Wk,
                                                   float* __restrict__ qe_t,
                                                   float* __restrict__ ke)
{
    __shared__ float  Xs[8][260];        // 8 rows x full K (=256), padded
    __shared__ float4 part[4][8][32];    // [wave][m][h-group] partial sums

    const int t = threadIdx.x;
    const bool isQ = (blockIdx.x < 512);
    const int blk  = isQ ? blockIdx.x : (blockIdx.x - 512);
    const int rows0 = blk * 8;
    const float* X = isQ ? query : key;
    const float* W = isQ ? Wq : Wk;

    // ---- stage X tile: 8 rows x 256 k (8 KB) ----
    {
        const int r = t >> 5;            // 0..7
        const int c = (t & 31) * 8;      // 0..248
        const float4 x0 = *(const float4*)(X + (size_t)(rows0 + r) * QD + c);
        const float4 x1 = *(const float4*)(X + (size_t)(rows0 + r) * QD + c + 4);
        *(float4*)&Xs[r][c]     = x0;
        *(float4*)&Xs[r][c + 4] = x1;
    }
    __syncthreads();

    const int w    = t >> 6;
    const int lane = t & 63;
    const int hg   = lane & 31;          // h4 = hg*4
    const int mb   = lane >> 5;          // 0/1; lane covers m = mb, mb+2, mb+4, mb+6

    float4 acc[4];
#pragma unroll
    for (int i = 0; i < 4; i++) acc[i] = make_float4(0.f, 0.f, 0.f, 0.f);

    const int kbase = w * 64;
#pragma unroll 4
    for (int kk = 0; kk < 64; kk++) {
        const int k = kbase + kk;
        const float4 wv = *(const float4*)(W + (size_t)k * HD + hg * 4);
#pragma unroll
        for (int mi = 0; mi < 4; mi++) {
            const float xv = Xs[mb + mi * 2][k];
            acc[mi].x += xv * wv.x;
            acc[mi].y += xv * wv.y;
            acc[mi].z += xv * wv.z;
            acc[mi].w += xv * wv.w;
        }
    }
#pragma unroll
    for (int mi = 0; mi < 4; mi++) part[w][mb + mi * 2][hg] = acc[mi];
    __syncthreads();

    // ---- reduce 4 partials, exp, store ----
    {
        const int m   = t >> 5;          // 0..7
        const int hg2 = t & 31;          // 0..31
        float4 s = part[0][m][hg2];
        const float4 p1 = part[1][m][hg2];
        const float4 p2 = part[2][m][hg2];
        const float4 p3 = part[3][m][hg2];
        s.x += p1.x + p2.x + p3.x;
        s.y += p1.y + p2.y + p3.y;
        s.z += p1.z + p2.z + p3.z;
        s.w += p1.w + p2.w + p3.w;
        float4 e = make_float4(fast_exp2(s.x * SCALE2), fast_exp2(s.y * SCALE2),
                               fast_exp2(s.z * SCALE2), fast_exp2(s.w * SCALE2));
        const int row = rows0 + m;
        if (isQ) {
            const int b = row >> 8, q = row & 255;
            float* base = qe_t + ((size_t)b * HD + hg2 * 4) * LQ + q;
            base[0 * LQ] = e.x;
            base[1 * LQ] = e.y;
            base[2 * LQ] = e.z;
            base[3 * LQ] = e.w;
        } else {
            *(float4*)(ke + (size_t)row * HD + hg2 * 4) = e;
        }
    }
}

// ---------------------------------------------------------------------------
// attn_kernel: 1024 blocks x 256 threads. Block = (b, 4 consecutive k).
// Phase 1: thread = q: score[k][q] = sumv - 2*sum_h v[h]*rcp(1 + qe[h][q]*ke[k][h])
// Phase 2: wave w -> softmax over q for k=w; write attention + attn_T[q][k] LDS
// Phase 3: wave w -> q-range [w*64,w*64+64), all 4 k; LDS partial reduce -> context
// ---------------------------------------------------------------------------
__global__ __launch_bounds__(256) void attn_kernel(const float* __restrict__ qe_t,
                                                   const float* __restrict__ ke,
                                                   const float* __restrict__ v,
                                                   const float* __restrict__ value,
                                                   float* __restrict__ out)
{
    __shared__ float  score_s[4][260];
    __shared__ float  attn_T[256][4];    // [q][k] -> float4 row per q
    __shared__ float2 partc[4][4][64];   // [wave][k][vd-pair]

    const int t  = threadIdx.x;
    const int b  = blockIdx.x >> 6;
    const int k0 = (blockIdx.x & 63) << 2;

    const float* qeb = qe_t + (size_t)b * HD * LQ;        // [h][q], holds e^{2qp}
    const float* keb = ke + ((size_t)b * LK + k0) * HD;   // 4 rows, e^{2kp}

    // ---- Phase 1 ----
    float acc0 = 0.f, acc1 = 0.f, acc2 = 0.f, acc3 = 0.f;
    const int q = t;
#pragma unroll 2
    for (int h0 = 0; h0 < HD; h0 += 8) {
        float qv[8];
#pragma unroll
        for (int j = 0; j < 8; j++) qv[j] = qeb[(size_t)(h0 + j) * LQ + q];
#pragma unroll
        for (int j = 0; j < 8; j++) {
            const float vh = v[h0 + j];
            acc0 += vh * fast_rcp(qv[j] * keb[0 * HD + h0 + j] + 1.0f);
            acc1 += vh * fast_rcp(qv[j] * keb[1 * HD + h0 + j] + 1.0f);
            acc2 += vh * fast_rcp(qv[j] * keb[2 * HD + h0 + j] + 1.0f);
            acc3 += vh * fast_rcp(qv[j] * keb[3 * HD + h0 + j] + 1.0f);
        }
    }
    float sumv = 0.f;  // wave-uniform, scalar pipe
#pragma unroll
    for (int h = 0; h < HD; h++) sumv += v[h];

    score_s[0][q] = sumv - 2.f * acc0;
    score_s[1][q] = sumv - 2.f * acc1;
    score_s[2][q] = sumv - 2.f * acc2;
    score_s[3][q] = sumv - 2.f * acc3;
    __syncthreads();

    // ---- Phase 2: softmax over q, wave w handles k=w ----
    const int w = t >> 6, lane = t & 63;
    {
        float x0 = score_s[w][lane];
        float x1 = score_s[w][lane + 64];
        float x2 = score_s[w][lane + 128];
        float x3 = score_s[w][lane + 192];
        float m = fmaxf(fmaxf(x0, x1), fmaxf(x2, x3));
#pragma unroll
        for (int off = 32; off >= 1; off >>= 1) m = fmaxf(m, __shfl_xor(m, off));
        float e0 = fast_exp2((x0 - m) * L2E);
        float e1 = fast_exp2((x1 - m) * L2E);
        float e2 = fast_exp2((x2 - m) * L2E);
        float e3 = fast_exp2((x3 - m) * L2E);
        float s = e0 + e1 + e2 + e3;
#pragma unroll
        for (int off = 32; off >= 1; off >>= 1) s += __shfl_xor(s, off);
        const float rs = fast_rcp(s);
        e0 *= rs; e1 *= rs; e2 *= rs; e3 *= rs;
        attn_T[lane][w]       = e0;
        attn_T[lane + 64][w]  = e1;
        attn_T[lane + 128][w] = e2;
        attn_T[lane + 192][w] = e3;
        float* ao = out + CTX_SIZE + ((size_t)(b * LK + k0 + w)) * LQ;
        ao[lane]       = e0;
        ao[lane + 64]  = e1;
        ao[lane + 128] = e2;
        ao[lane + 192] = e3;
    }
    __syncthreads();

    // ---- Phase 3: context. Wave w sums its q-range for all 4 k ----
    {
        const int vd2 = lane * 2;
        const float* valb = value + (size_t)b * LQ * VD;
        float2 c0 = {0.f, 0.f}, c1 = {0.f, 0.f}, c2 = {0.f, 0.f}, c3 = {0.f, 0.f};
#pragma unroll 4
        for (int i = 0; i < 64; i++) {
            const int q2 = (w << 6) + i;
            const float4 a = *(const float4*)&attn_T[q2][0];
            const float2 vv = *(const float2*)(valb + (size_t)q2 * VD + vd2);
            c0.x += a.x * vv.x; c0.y += a.x * vv.y;
            c1.x += a.y * vv.x; c1.y += a.y * vv.y;
            c2.x += a.z * vv.x; c2.y += a.z * vv.y;
            c3.x += a.w * vv.x; c3.y += a.w * vv.y;
        }
        partc[w][0][lane] = c0;
        partc[w][1][lane] = c1;
        partc[w][2][lane] = c2;
        partc[w][3][lane] = c3;
    }
    __syncthreads();
    {
        const int kg = t >> 6, l2 = t & 63;
        const float2 p0 = partc[0][kg][l2];
        const float2 p1 = partc[1][kg][l2];
        const float2 p2 = partc[2][kg][l2];
        const float2 p3 = partc[3][kg][l2];
        float2 s;
        s.x = p0.x + p1.x + p2.x + p3.x;
        s.y = p0.y + p1.y + p2.y + p3.y;
        *(float2*)(out + ((size_t)(b * LK + k0 + kg)) * VD + l2 * 2) = s;
    }
}

extern "C" void kernel_launch(void* const* d_in, const int* in_sizes, int n_in,
                              void* d_out, int out_size, void* d_ws, size_t ws_size,
                              hipStream_t stream)
{
    const float* query = (const float*)d_in[0];
    const float* key   = (const float*)d_in[1];
    const float* value = (const float*)d_in[2];
    const float* Wq    = (const float*)d_in[3];
    const float* Wk    = (const float*)d_in[4];
    const float* v     = (const float*)d_in[5];
    float* out = (float*)d_out;

    float* qe_t = (float*)d_ws;                      // [B][HD][LQ], e^{2qp}
    float* kew  = qe_t + (size_t)B_ * HD * LQ;       // [B][LK][HD], e^{2kp}

    proj_kernel<<<dim3(1024), 256, 0, stream>>>(query, key, Wq, Wk, qe_t, kew);
    attn_kernel<<<dim3(1024), 256, 0, stream>>>(qe_t, kew, v, value, out);
}